// Round 22
// baseline (235.463 us; speedup 1.0000x reference)
//
#include <hip/hip_runtime.h>
#include <hip/hip_bf16.h>
#include <stdint.h>

// N=16, M=4, D=32, K=256, H=64, W=64 ; P = 262144 pixels
// outputs (concat, read back as f32): sample (P*256), code (P, as float), logit (P*256)
// d_ws: [c2tab 4KB][cbh 64KB][cbl 64KB][count 64B][list 16KB]
// R22 = R21 (MFMA inter, validated) with the rare exact-resolve path MOVED OUT
// of the hot kernel into a deferred fixup kernel (flag list via atomicAdd).
// Hot kernel: top-2 tracking only, no plog/exact code. Fixup: fully-validated
// exact chains, block argmax, rewrites code+sample row. Deterministic.

#define TINY_F 1.17549435082228750797e-38f
#define LN2F   0.69314718055994530942f
#define MARGIN 4.0e-4f
#define LISTCAP 4096u

constexpr int KK = 256;
constexpr int DD = 32;

typedef __attribute__((ext_vector_type(8))) short bf16x8;
typedef __attribute__((ext_vector_type(4))) float f32x4;

// XLA:CPU vectorized log (validated R2, code absmax == 0). Fixup path only.
__device__ __forceinline__ float plog_xla(float xin) {
  #pragma clang fp contract(off)
  uint32_t ix = __float_as_uint(xin);
  int e_i = (int)(ix >> 23) - 126;
  float x = __uint_as_float((ix & 0x007FFFFFu) | 0x3F000000u);
  float e = (float)e_i;
  bool lt = x < 0.707106781186547524f;
  float tmp = lt ? x : 0.0f;
  x = x - 1.0f;
  e = e - (lt ? 1.0f : 0.0f);
  x = x + tmp;
  float z  = x * x;
  float x3 = z * x;
  float y  =  7.0376836292e-2f * x + (-1.1514610310e-1f);
  float y1 = -1.2420140846e-1f * x +   1.4249322787e-1f;
  float y2 =  2.0000714765e-1f * x + (-2.4999993993e-1f);
  y  = y  * x +   1.1676998740e-1f;
  y1 = y1 * x + (-1.6668057665e-1f);
  y2 = y2 * x +   3.3333331174e-1f;
  y  = y * x3 + y1;
  y  = y * x3 + y2;
  y  = y * x3;
  y  = y + e * (-2.12194440e-4f);
  x  = x - 0.5f * z;
  x  = x + y;
  x  = x + e * 0.693359375f;
  return x;
}

__device__ __forceinline__ float sumsq_unfused(const float* v) {
  #pragma clang fp contract(off)
  float a = 0.0f;
  #pragma unroll
  for (int d = 0; d < 32; d++) a = a + v[d] * v[d];
  return a;
}

__device__ __forceinline__ void threefry2x32(uint32_t k0, uint32_t k1,
                                             uint32_t x0, uint32_t x1,
                                             uint32_t& o0, uint32_t& o1) {
  uint32_t ks2 = k0 ^ k1 ^ 0x1BD11BDAu;
  x0 += k0; x1 += k1;
#define TF_RND(r) { x0 += x1; x1 = (x1 << (r)) | (x1 >> (32 - (r))); x1 ^= x0; }
  TF_RND(13) TF_RND(15) TF_RND(26) TF_RND(6)
  x0 += k1; x1 += ks2 + 1u;
  TF_RND(17) TF_RND(29) TF_RND(16) TF_RND(24)
  x0 += ks2; x1 += k0 + 2u;
  TF_RND(13) TF_RND(15) TF_RND(26) TF_RND(6)
  x0 += k0; x1 += k1 + 3u;
  TF_RND(17) TF_RND(29) TF_RND(16) TF_RND(24)
  x0 += k1; x1 += ks2 + 4u;
  TF_RND(13) TF_RND(15) TF_RND(26) TF_RND(6)
  x0 += ks2; x1 += k0 + 5u;
#undef TF_RND
  o0 = x0; o1 = x1;
}

// EXACT gumbel (validated R2). Fixup path only.
__device__ __forceinline__ float gumbel_from_bits(uint32_t bits) {
  uint32_t mant = bits >> 9;
  float f = __uint_as_float(0x3F800000u | mant) - 1.0f;
  float u = mant ? f : TINY_F;
  float t = -plog_xla(u);
  return -plog_xla(t);
}

// FAST gumbel via v_log_f32 (scan only; certified by margin).
__device__ __forceinline__ float gumbel_fast(uint32_t bits) {
  uint32_t mant = bits >> 9;
  float f = __uint_as_float(0x3F800000u | mant) - 1.0f;
  float u = mant ? f : TINY_F;
  float t = -(__log2f(u) * LN2F);
  return -(__log2f(t) * LN2F);
}

__device__ __forceinline__ short bf16_rn_bits(float v) {
  __hip_bfloat16 h = __float2bfloat16(v);
  return *reinterpret_cast<short*>(&h);
}
__device__ __forceinline__ float bf16_to_f(short s) {
  __hip_bfloat16 h = *reinterpret_cast<__hip_bfloat16*>(&s);
  return __bfloat162float(h);
}

// prologue: exact c2 table (validated unfused chain) + bf16 hi/lo tables
// + zero the fixup counter (graph-safe, no extra API calls)
__global__ __launch_bounds__(256)
void mcq_prep(const float* __restrict__ cb, float* __restrict__ c2tab,
              short* __restrict__ cbh, short* __restrict__ cbl,
              uint32_t* __restrict__ count) {
  if (blockIdx.x == 0 && threadIdx.x == 0) *count = 0u;
  const int m = blockIdx.x;            // 4
  const int k = threadIdx.x;           // 256
  const float* row = cb + ((size_t)m * KK + k) * DD;
  float cr[DD];
  #pragma unroll
  for (int j = 0; j < 8; j++) {
    float4 q = ((const float4*)row)[j];
    cr[4*j+0] = q.x; cr[4*j+1] = q.y; cr[4*j+2] = q.z; cr[4*j+3] = q.w;
  }
  c2tab[m * KK + k] = sumsq_unfused(cr);
  short* hrow = cbh + ((size_t)m * KK + k) * DD;
  short* lrow = cbl + ((size_t)m * KK + k) * DD;
  #pragma unroll
  for (int d = 0; d < DD; d++) {
    float v = cr[d];
    short hb = bf16_rn_bits(v);
    float hf = bf16_to_f(hb);
    short lb = bf16_rn_bits(v - hf);
    hrow[d] = hb; lrow[d] = lb;
  }
}

__global__ __launch_bounds__(256, 8)
void mcq_mfma(const float* __restrict__ x, const float* __restrict__ c2tab,
              const short* __restrict__ cbh, const short* __restrict__ cbl,
              float* __restrict__ sample, float* __restrict__ code,
              float* __restrict__ logit, uint32_t* __restrict__ count,
              uint32_t* __restrict__ list) {
  __shared__ int s_wb[64];

  const int t   = threadIdx.x;
  const int l   = t & 63, wvw = t >> 6;      // lane, wave
  const int grp = l >> 4;                    // 0..3
  const int pbase = blockIdx.x << 6;         // 4096 blocks x 64 px
  const int nm  = pbase >> 12;               // uniform (64 | 4096)
  const int m   = nm & 3;
  const int pxl = (wvw << 4) + (l & 15);     // 0..63
  const int gp  = pbase + pxl;
  const int hw  = (pbase & 4095) + pxl;

  const float* c2m = c2tab + m * KK;
  const short* chm = cbh + (size_t)m * (KK * DD);
  const short* clm = cbl + (size_t)m * (KK * DD);
  const float* xb  = x + (size_t)nm * 131072;

  // B-frag (x) hi/lo + fast x2 (fast path only)
  bf16x8 bh, bl;
  float x2p = 0.0f;
  #pragma unroll
  for (int j = 0; j < 8; j++) {
    const int d = (grp << 3) + j;
    float v = xb[(size_t)d * 4096 + hw];
    short hbits = bf16_rn_bits(v);
    float hf = bf16_to_f(hbits);
    short lbits = bf16_rn_bits(v - hf);
    bh[j] = hbits; bl[j] = lbits;
    x2p = __builtin_fmaf(v, v, x2p);
  }
  x2p += __shfl_xor(x2p, 16, 64);
  x2p += __shfl_xor(x2p, 32, 64);
  const float x2f = x2p;

  float* lrowg = logit + ((size_t)gp << 8) + (grp << 2);
  const uint32_t lbase = (uint32_t)gp << 8;

  float best = -__builtin_inff(), sec = -__builtin_inff();
  int bi1 = 0;

  #pragma unroll 1
  for (int kt = 0; kt < 16; kt++) {
    const int krow = (kt << 4) + (l & 15);
    const bf16x8 ah = *(const bf16x8*)(chm + (size_t)krow * DD + (grp << 3));
    const bf16x8 al = *(const bf16x8*)(clm + (size_t)krow * DD + (grp << 3));
    f32x4 acc = {0.0f, 0.0f, 0.0f, 0.0f};
    acc = __builtin_amdgcn_mfma_f32_16x16x32_bf16(al, bh, acc, 0, 0, 0);
    acc = __builtin_amdgcn_mfma_f32_16x16x32_bf16(ah, bl, acc, 0, 0, 0);
    acc = __builtin_amdgcn_mfma_f32_16x16x32_bf16(ah, bh, acc, 0, 0, 0);
    const float4 c2q = *(const float4*)(c2m + (kt << 4) + (grp << 2));
    const int kb = (kt << 4) + (grp << 2);

    float L0, L1, L2, L3;
#define ELEM(R, C2V, LV)                                                       \
    {                                                                          \
      float dist = (x2f + (C2V)) - 2.0f * acc[R];                              \
      LV = __log2f(dist) * LN2F;                                               \
      uint32_t v0_, v1_;                                                       \
      threefry2x32(0u, 42u, 0u, lbase | (uint32_t)(kb + (R)), v0_, v1_);       \
      float p_ = gumbel_fast(v0_ ^ v1_) + LV;                                  \
      if (p_ > best) { sec = best; best = p_; bi1 = kb + (R); }                \
      else if (p_ > sec) sec = p_;                                             \
    }
    ELEM(0, c2q.x, L0)
    ELEM(1, c2q.y, L1)
    ELEM(2, c2q.z, L2)
    ELEM(3, c2q.w, L3)
#undef ELEM
    *(float4*)(lrowg + (kt << 4)) = make_float4(L0, L1, L2, L3);
  }

  // merge top-2 across the 4 lanes sharing this px (first-occurrence ties)
#define MERGE2(OFF)                                                            \
  {                                                                            \
    float ob = __shfl_xor(best, OFF, 64);                                      \
    float os = __shfl_xor(sec,  OFF, 64);                                      \
    int  oi1 = __shfl_xor(bi1,  OFF, 64);                                      \
    bool take = (ob > best) || (ob == best && oi1 < bi1);                      \
    float nb  = take ? ob : best;                                              \
    int   ni  = take ? oi1 : bi1;                                              \
    float lsr = take ? best : ob;    /* loser's best */                        \
    float wsr = take ? os : sec;     /* winner's second */                     \
    best = nb; bi1 = ni;                                                       \
    sec = fmaxf(wsr, lsr);                                                     \
  }
  MERGE2(16)
  MERGE2(32)
#undef MERGE2

  if (l < 16) {
    code[gp] = (float)bi1;           // provisional if uncertified
    s_wb[pxl] = bi1;
    if (!(best - sec > MARGIN)) {
      uint32_t idx = atomicAdd(count, 1u);
      if (idx < LISTCAP) list[idx] = (uint32_t)gp;
    }
  }
  __syncthreads();

  // cooperative one-hot sample: wave wvw writes rows [wvw*16, wvw*16+16)
  const int k0 = l << 2;
  for (int r = wvw * 16; r < wvw * 16 + 16; r++) {
    const int wr = s_wb[r];
    float4 v;
    v.x = (wr == k0 + 0) ? 1.0f : 0.0f;
    v.y = (wr == k0 + 1) ? 1.0f : 0.0f;
    v.z = (wr == k0 + 2) ? 1.0f : 0.0f;
    v.w = (wr == k0 + 3) ? 1.0f : 0.0f;
    ((float4*)(sample + (((size_t)(pbase + r)) << 8)))[l] = v;
  }
}

// fixup: exact recompute of flagged pixels (fully validated chains).
// One block (256 threads = 256 k) per flagged pixel, grid-stride.
__global__ __launch_bounds__(256)
void mcq_fix(const float* __restrict__ x, const float* __restrict__ cb,
             const float* __restrict__ c2tab, const uint32_t* __restrict__ count,
             const uint32_t* __restrict__ list, float* __restrict__ sample,
             float* __restrict__ code) {
  __shared__ unsigned long long s_scr[256];
  const uint32_t n = min(*count, LISTCAP);
  const int t = threadIdx.x;

  for (uint32_t i = blockIdx.x; i < n; i += gridDim.x) {
    const int gp = (int)list[i];
    const int nm = gp >> 12;
    const int m  = nm & 3;
    const int hw = gp & 4095;
    const float* cbm = cb + (size_t)m * (KK * DD);
    const float* c2m = c2tab + m * KK;
    const float* xb  = x + (size_t)nm * 131072;
    const uint32_t lbase = (uint32_t)gp << 8;

    // exact x2 (validated unfused ascending chain)
    float x2e;
    {
      #pragma clang fp contract(off)
      float a = 0.0f;
      #pragma unroll 1
      for (int d = 0; d < DD; d++) {
        float v = xb[(size_t)d * 4096 + hw];
        a = a + v * v;
      }
      x2e = a;
    }
    // exact inter for row k=t (validated fused ascending chain)
    float inter = 0.0f;
    {
      const float* rp = cbm + (size_t)t * DD;
      #pragma unroll 1
      for (int j = 0; j < 8; j++) {
        float4 q = *(const float4*)(rp + (j << 2));
        inter = __builtin_fmaf(xb[(size_t)((j<<2)+0)*4096 + hw], q.x, inter);
        inter = __builtin_fmaf(xb[(size_t)((j<<2)+1)*4096 + hw], q.y, inter);
        inter = __builtin_fmaf(xb[(size_t)((j<<2)+2)*4096 + hw], q.z, inter);
        inter = __builtin_fmaf(xb[(size_t)((j<<2)+3)*4096 + hw], q.w, inter);
      }
    }
    float dist = (x2e + c2m[t]) - 2.0f * inter;
    float L = plog_xla(dist);
    uint32_t v0, v1;
    threefry2x32(0u, 42u, 0u, lbase | (uint32_t)t, v0, v1);
    float phi = gumbel_from_bits(v0 ^ v1) + L;

    // order-preserving pack + max-reduce; ties -> smaller k (first occurrence)
    uint32_t pb = __float_as_uint(phi);
    pb ^= (uint32_t)(((int32_t)pb) >> 31) | 0x80000000u;
    s_scr[t] = ((unsigned long long)pb << 32) | (unsigned long long)(255 - t);
    __syncthreads();
    for (int st = 128; st > 0; st >>= 1) {
      if (t < st) {
        unsigned long long o = s_scr[t + st];
        if (o > s_scr[t]) s_scr[t] = o;
      }
      __syncthreads();
    }
    const int w = 255 - (int)(s_scr[0] & 0xFFu);
    if (t == 0) code[gp] = (float)w;
    sample[((size_t)gp << 8) + t] = (t == w) ? 1.0f : 0.0f;
    __syncthreads();
  }
}

extern "C" void kernel_launch(void* const* d_in, const int* in_sizes, int n_in,
                              void* d_out, int out_size, void* d_ws, size_t ws_size,
                              hipStream_t stream) {
  const float* x  = (const float*)d_in[0];
  const float* cb = (const float*)d_in[1];

  float* out_f  = (float*)d_out;
  float* sample = out_f;                       // 67108864
  float* code   = out_f + 67108864;            // 262144 (as float)
  float* logit  = out_f + 67108864 + 262144;   // 67108864

  float*    c2tab = (float*)d_ws;                               // 4 KB
  short*    cbh   = (short*)((char*)d_ws + 4096);               // 64 KB
  short*    cbl   = (short*)((char*)d_ws + 4096 + 65536);       // 64 KB
  uint32_t* count = (uint32_t*)((char*)d_ws + 4096 + 131072);   // 64 B slot
  uint32_t* list  = (uint32_t*)((char*)d_ws + 4096 + 131072 + 64); // 16 KB

  mcq_prep<<<4, 256, 0, stream>>>(cb, c2tab, cbh, cbl, count);
  mcq_mfma<<<4096, 256, 0, stream>>>(x, c2tab, cbh, cbl, sample, code, logit,
                                     count, list);
  mcq_fix<<<1024, 256, 0, stream>>>(x, cb, c2tab, count, list, sample, code);
}

// Round 24
// 206.110 us; speedup vs baseline: 1.1424x; 1.1424x over previous
//
#include <hip/hip_runtime.h>
#include <hip/hip_bf16.h>
#include <stdint.h>

// N=16, M=4, D=32, K=256, H=64, W=64 ; P = 262144 pixels
// outputs (concat, read back as f32): sample (P*256), code (P, as float), logit (P*256)
// d_ws: [c2tab 4KB][cbh 64KB][cbl 64KB]
// R24 = R23 with the nontemporal stores fixed to use clang native vector type
// (f32x4 ext_vector) instead of HIP float4 (class type rejected by builtin).
// R21 core (champion 220.4 us): MFMA inter + (256,8) tier + merged prologue.

#define TINY_F 1.17549435082228750797e-38f
#define LN2F   0.69314718055994530942f
#define MARGIN 4.0e-4f

constexpr int KK = 256;
constexpr int DD = 32;

typedef __attribute__((ext_vector_type(8))) short bf16x8;
typedef __attribute__((ext_vector_type(4))) float f32x4;

// XLA:CPU vectorized log (validated R2, code absmax == 0). Exact path only.
__device__ __forceinline__ float plog_xla(float xin) {
  #pragma clang fp contract(off)
  uint32_t ix = __float_as_uint(xin);
  int e_i = (int)(ix >> 23) - 126;
  float x = __uint_as_float((ix & 0x007FFFFFu) | 0x3F000000u);
  float e = (float)e_i;
  bool lt = x < 0.707106781186547524f;
  float tmp = lt ? x : 0.0f;
  x = x - 1.0f;
  e = e - (lt ? 1.0f : 0.0f);
  x = x + tmp;
  float z  = x * x;
  float x3 = z * x;
  float y  =  7.0376836292e-2f * x + (-1.1514610310e-1f);
  float y1 = -1.2420140846e-1f * x +   1.4249322787e-1f;
  float y2 =  2.0000714765e-1f * x + (-2.4999993993e-1f);
  y  = y  * x +   1.1676998740e-1f;
  y1 = y1 * x + (-1.6668057665e-1f);
  y2 = y2 * x +   3.3333331174e-1f;
  y  = y * x3 + y1;
  y  = y * x3 + y2;
  y  = y * x3;
  y  = y + e * (-2.12194440e-4f);
  x  = x - 0.5f * z;
  x  = x + y;
  x  = x + e * 0.693359375f;
  return x;
}

__device__ __forceinline__ float sumsq_unfused(const float* v) {
  #pragma clang fp contract(off)
  float a = 0.0f;
  #pragma unroll
  for (int d = 0; d < 32; d++) a = a + v[d] * v[d];
  return a;
}

__device__ __forceinline__ void threefry2x32(uint32_t k0, uint32_t k1,
                                             uint32_t x0, uint32_t x1,
                                             uint32_t& o0, uint32_t& o1) {
  uint32_t ks2 = k0 ^ k1 ^ 0x1BD11BDAu;
  x0 += k0; x1 += k1;
#define TF_RND(r) { x0 += x1; x1 = (x1 << (r)) | (x1 >> (32 - (r))); x1 ^= x0; }
  TF_RND(13) TF_RND(15) TF_RND(26) TF_RND(6)
  x0 += k1; x1 += ks2 + 1u;
  TF_RND(17) TF_RND(29) TF_RND(16) TF_RND(24)
  x0 += ks2; x1 += k0 + 2u;
  TF_RND(13) TF_RND(15) TF_RND(26) TF_RND(6)
  x0 += k0; x1 += k1 + 3u;
  TF_RND(17) TF_RND(29) TF_RND(16) TF_RND(24)
  x0 += k1; x1 += ks2 + 4u;
  TF_RND(13) TF_RND(15) TF_RND(26) TF_RND(6)
  x0 += ks2; x1 += k0 + 5u;
#undef TF_RND
  o0 = x0; o1 = x1;
}

// EXACT gumbel (validated R2). Resolve path only.
__device__ __forceinline__ float gumbel_from_bits(uint32_t bits) {
  uint32_t mant = bits >> 9;
  float f = __uint_as_float(0x3F800000u | mant) - 1.0f;
  float u = mant ? f : TINY_F;
  float t = -plog_xla(u);
  return -plog_xla(t);
}

// FAST gumbel via v_log_f32 (scan only; certified by margin).
__device__ __forceinline__ float gumbel_fast(uint32_t bits) {
  uint32_t mant = bits >> 9;
  float f = __uint_as_float(0x3F800000u | mant) - 1.0f;
  float u = mant ? f : TINY_F;
  float t = -(__log2f(u) * LN2F);
  return -(__log2f(t) * LN2F);
}

__device__ __forceinline__ short bf16_rn_bits(float v) {
  __hip_bfloat16 h = __float2bfloat16(v);
  return *reinterpret_cast<short*>(&h);
}
__device__ __forceinline__ float bf16_to_f(short s) {
  __hip_bfloat16 h = *reinterpret_cast<__hip_bfloat16*>(&s);
  return __bfloat162float(h);
}

#define TRACK(P, KL, BEST, SEC, THI, I1, I2)                                   \
  if ((P) > BEST) { THI = SEC; SEC = BEST; I2 = I1; BEST = (P); I1 = (KL); }   \
  else if ((P) > SEC) { THI = SEC; SEC = (P); I2 = (KL); }                     \
  else if ((P) > THI) THI = (P);

// exact phi, reloading x fresh (validated fused ascending chain + plog gumbel)
#define EXACT_PHI_R(OUT, KI)                                                   \
  {                                                                            \
    const int _ki = (KI);                                                      \
    const float* _rp = cbm + (size_t)_ki * DD;                                 \
    float _in = 0.0f;                                                          \
    _Pragma("unroll 1")                                                        \
    for (int _j = 0; _j < 8; _j++) {                                           \
      float4 _q = *(const float4*)(_rp + (_j << 2));                           \
      _in = __builtin_fmaf(xb[(size_t)((_j<<2)+0)*4096 + hw], _q.x, _in);      \
      _in = __builtin_fmaf(xb[(size_t)((_j<<2)+1)*4096 + hw], _q.y, _in);      \
      _in = __builtin_fmaf(xb[(size_t)((_j<<2)+2)*4096 + hw], _q.z, _in);      \
      _in = __builtin_fmaf(xb[(size_t)((_j<<2)+3)*4096 + hw], _q.w, _in);      \
    }                                                                          \
    float _d = (x2e + c2m[_ki]) - 2.0f * _in;                                  \
    float _L = plog_xla(_d);                                                   \
    uint32_t _v0, _v1;                                                         \
    threefry2x32(0u, 42u, 0u, lbase | (uint32_t)_ki, _v0, _v1);                \
    OUT = gumbel_from_bits(_v0 ^ _v1) + _L;                                    \
  }

// prologue: exact c2 table (validated unfused chain) + bf16 hi/lo tables
__global__ __launch_bounds__(256)
void mcq_prep(const float* __restrict__ cb, float* __restrict__ c2tab,
              short* __restrict__ cbh, short* __restrict__ cbl) {
  const int m = blockIdx.x;            // 4
  const int k = threadIdx.x;           // 256
  const float* row = cb + ((size_t)m * KK + k) * DD;
  float cr[DD];
  #pragma unroll
  for (int j = 0; j < 8; j++) {
    float4 q = ((const float4*)row)[j];
    cr[4*j+0] = q.x; cr[4*j+1] = q.y; cr[4*j+2] = q.z; cr[4*j+3] = q.w;
  }
  c2tab[m * KK + k] = sumsq_unfused(cr);
  short* hrow = cbh + ((size_t)m * KK + k) * DD;
  short* lrow = cbl + ((size_t)m * KK + k) * DD;
  #pragma unroll
  for (int d = 0; d < DD; d++) {
    float v = cr[d];
    short hb = bf16_rn_bits(v);
    float hf = bf16_to_f(hb);
    short lb = bf16_rn_bits(v - hf);
    hrow[d] = hb; lrow[d] = lb;
  }
}

__global__ __launch_bounds__(256, 8)
void mcq_mfma(const float* __restrict__ x, const float* __restrict__ cb,
              const float* __restrict__ c2tab, const short* __restrict__ cbh,
              const short* __restrict__ cbl, float* __restrict__ sample,
              float* __restrict__ code, float* __restrict__ logit) {
  __shared__ int s_wb[64];

  const int t   = threadIdx.x;
  const int l   = t & 63, wvw = t >> 6;      // lane, wave
  const int grp = l >> 4;                    // 0..3
  const int pbase = blockIdx.x << 6;         // 4096 blocks x 64 px
  const int nm  = pbase >> 12;               // uniform (64 | 4096)
  const int m   = nm & 3;
  const int pxl = (wvw << 4) + (l & 15);     // 0..63
  const int gp  = pbase + pxl;
  const int hw  = (pbase & 4095) + pxl;

  const float* cbm = cb + (size_t)m * (KK * DD);
  const float* c2m = c2tab + m * KK;
  const short* chm = cbh + (size_t)m * (KK * DD);
  const short* clm = cbl + (size_t)m * (KK * DD);
  const float* xb  = x + (size_t)nm * 131072;

  // B-frag (x) hi/lo + fast x2 (fast path only; exact x2 recomputed on resolve)
  bf16x8 bh, bl;
  float x2p = 0.0f;
  #pragma unroll
  for (int j = 0; j < 8; j++) {
    const int d = (grp << 3) + j;
    float v = xb[(size_t)d * 4096 + hw];
    short hbits = bf16_rn_bits(v);
    float hf = bf16_to_f(hbits);
    short lbits = bf16_rn_bits(v - hf);
    bh[j] = hbits; bl[j] = lbits;
    x2p = __builtin_fmaf(v, v, x2p);
  }
  x2p += __shfl_xor(x2p, 16, 64);
  x2p += __shfl_xor(x2p, 32, 64);
  const float x2f = x2p;

  float* lrowg = logit + ((size_t)gp << 8) + (grp << 2);
  const uint32_t lbase = (uint32_t)gp << 8;

  float best = -__builtin_inff(), sec = -__builtin_inff(), thi = -__builtin_inff();
  int bi1 = 0, bi2 = 0;

  #pragma unroll 1
  for (int kt = 0; kt < 16; kt++) {
    const int krow = (kt << 4) + (l & 15);
    const bf16x8 ah = *(const bf16x8*)(chm + (size_t)krow * DD + (grp << 3));
    const bf16x8 al = *(const bf16x8*)(clm + (size_t)krow * DD + (grp << 3));
    f32x4 acc = {0.0f, 0.0f, 0.0f, 0.0f};
    acc = __builtin_amdgcn_mfma_f32_16x16x32_bf16(al, bh, acc, 0, 0, 0);
    acc = __builtin_amdgcn_mfma_f32_16x16x32_bf16(ah, bl, acc, 0, 0, 0);
    acc = __builtin_amdgcn_mfma_f32_16x16x32_bf16(ah, bh, acc, 0, 0, 0);
    const float4 c2q = *(const float4*)(c2m + (kt << 4) + (grp << 2));
    const int kb = (kt << 4) + (grp << 2);

    float L0, L1, L2, L3;
#define ELEM(R, C2V, LV)                                                       \
    {                                                                          \
      float dist = (x2f + (C2V)) - 2.0f * acc[R];                              \
      LV = __log2f(dist) * LN2F;                                               \
      uint32_t v0_, v1_;                                                       \
      threefry2x32(0u, 42u, 0u, lbase | (uint32_t)(kb + (R)), v0_, v1_);       \
      float p_ = gumbel_fast(v0_ ^ v1_) + LV;                                  \
      const int kk_ = kb + (R);                                                \
      TRACK(p_, kk_, best, sec, thi, bi1, bi2)                                 \
    }
    ELEM(0, c2q.x, L0)
    ELEM(1, c2q.y, L1)
    ELEM(2, c2q.z, L2)
    ELEM(3, c2q.w, L3)
#undef ELEM
    // nontemporal streaming store (never re-read; keep L2 for the tables)
    f32x4 Lq = {L0, L1, L2, L3};
    __builtin_nontemporal_store(Lq, (f32x4*)(lrowg + (kt << 4)));
  }

  // merge top-3 across the 4 lanes sharing this px (first-occurrence ties)
#define MERGE(OFF)                                                             \
  {                                                                            \
    float ob = __shfl_xor(best, OFF, 64);                                      \
    float os = __shfl_xor(sec,  OFF, 64);                                      \
    float ot = __shfl_xor(thi,  OFF, 64);                                      \
    int  oi1 = __shfl_xor(bi1,  OFF, 64);                                      \
    int  oi2 = __shfl_xor(bi2,  OFF, 64);                                      \
    bool take = (ob > best) || (ob == best && oi1 < bi1);                      \
    float wb = take ? ob : best, ws2 = take ? os : sec, wt = take ? ot : thi;  \
    int  wi1 = take ? oi1 : bi1, wi2 = take ? oi2 : bi2;                       \
    float lb = take ? best : ob, ls = take ? sec : os;                         \
    int  li1 = take ? bi1 : oi1;                                               \
    bool s2 = (ws2 > lb) || (ws2 == lb && wi2 < li1);                          \
    best = wb; bi1 = wi1;                                                      \
    if (s2) { sec = ws2; bi2 = wi2; thi = fmaxf(wt, lb); }                     \
    else    { sec = lb;  bi2 = li1; thi = fmaxf(ws2, ls); }                    \
  }
  MERGE(16)
  MERGE(32)
#undef MERGE

  if (l < 16) {
    int w;
    if (best - sec > MARGIN) {
      w = bi1;
    } else {
      // exact x2 (validated unfused chain), fresh loads
      float x2e;
      {
        #pragma clang fp contract(off)
        float a = 0.0f;
        #pragma unroll 1
        for (int d = 0; d < DD; d++) {
          float v = xb[(size_t)d * 4096 + hw];
          a = a + v * v;
        }
        x2e = a;
      }
      if (best - thi > MARGIN) {
        int ka = bi1 < bi2 ? bi1 : bi2;
        int kb2 = bi1 < bi2 ? bi2 : bi1;
        float fa, fb;
        EXACT_PHI_R(fa, ka)
        EXACT_PHI_R(fb, kb2)
        w = (fb > fa) ? kb2 : ka;      // tie -> smaller k (first occurrence)
      } else {
        float bb = -__builtin_inff(); int wbb = 0;
        #pragma unroll 1
        for (int k2i = 0; k2i < KK; k2i++) {
          float ph;
          EXACT_PHI_R(ph, k2i)
          if (ph > bb) { bb = ph; wbb = k2i; }
        }
        w = wbb;
      }
    }
    code[gp] = (float)w;
    s_wb[pxl] = w;
  }
  __syncthreads();

  // cooperative one-hot sample: wave wvw writes rows [wvw*16, wvw*16+16)
  const int k0 = l << 2;
  for (int r = wvw * 16; r < wvw * 16 + 16; r++) {
    const int wr = s_wb[r];
    f32x4 v;
    v[0] = (wr == k0 + 0) ? 1.0f : 0.0f;
    v[1] = (wr == k0 + 1) ? 1.0f : 0.0f;
    v[2] = (wr == k0 + 2) ? 1.0f : 0.0f;
    v[3] = (wr == k0 + 3) ? 1.0f : 0.0f;
    __builtin_nontemporal_store(
        v, ((f32x4*)(sample + (((size_t)(pbase + r)) << 8))) + l);
  }
}

extern "C" void kernel_launch(void* const* d_in, const int* in_sizes, int n_in,
                              void* d_out, int out_size, void* d_ws, size_t ws_size,
                              hipStream_t stream) {
  const float* x  = (const float*)d_in[0];
  const float* cb = (const float*)d_in[1];

  float* out_f  = (float*)d_out;
  float* sample = out_f;                       // 67108864
  float* code   = out_f + 67108864;            // 262144 (as float)
  float* logit  = out_f + 67108864 + 262144;   // 67108864

  float* c2tab  = (float*)d_ws;                          // 4 KB
  short* cbh    = (short*)((char*)d_ws + 4096);          // 64 KB
  short* cbl    = (short*)((char*)d_ws + 4096 + 65536);  // 64 KB

  mcq_prep<<<4, 256, 0, stream>>>(cb, c2tab, cbh, cbl);
  mcq_mfma<<<4096, 256, 0, stream>>>(x, cb, c2tab, cbh, cbl, sample, code, logit);
}